// Round 2
// baseline (281.433 us; speedup 1.0000x reference)
//
#include <hip/hip_runtime.h>

// Problem: S=8192, K=1024, O=4096
// out_q[s,o] = clip(round(int8dot(x[s,:], w[o,:]) * sx*sw/sy[s]), -128, 127)
// d_out = [ out_q as float (S*O) | scale_y (S) ]

#define S_DIM 8192
#define K_DIM 1024
#define O_DIM 4096
#define BM 128
#define BN 128
#define BK 64

using i32x4 = __attribute__((ext_vector_type(4))) int;

// ---------------- pack: int32 -> int8 for x and w, plus scale_y passthrough ----
__global__ void pack_kernel(const int* __restrict__ xi, const int* __restrict__ wi,
                            const float* __restrict__ sy,
                            unsigned int* __restrict__ xq, unsigned int* __restrict__ wq,
                            float* __restrict__ out_sy) {
  const int idx = blockIdx.x * blockDim.x + threadIdx.x;
  const int nx = S_DIM * K_DIM / 4;  // 2M packed words
  const int nw = O_DIM * K_DIM / 4;  // 1M packed words
  if (idx < nx) {
    int4 v = ((const int4*)xi)[idx];
    unsigned int p = (v.x & 0xff) | ((v.y & 0xff) << 8) |
                     ((v.z & 0xff) << 16) | ((unsigned)(v.w & 0xff) << 24);
    xq[idx] = p;
  } else if (idx < nx + nw) {
    const int j = idx - nx;
    int4 v = ((const int4*)wi)[j];
    unsigned int p = (v.x & 0xff) | ((v.y & 0xff) << 8) |
                     ((v.z & 0xff) << 16) | ((unsigned)(v.w & 0xff) << 24);
    wq[j] = p;
  }
  if (idx < S_DIM) out_sy[idx] = sy[idx];
}

// ---------------- int8 MFMA GEMM, no-LDS flatmm style -------------------------
// Block: 256 threads = 4 waves in 2x2; each wave owns a 64x64 sub-tile as a
// 4x4 grid of 16x16 MFMA tiles. Fragments are loaded DIRECTLY from global
// (L2-resident: A slice re-read 2x/block, B tile re-read 64x across block
// rows -> ~768 MB L2 traffic ~22us at 34.5 TB/s). No LDS, no barriers in the
// K-loop: the compiler pipelines global_load_dwordx4 across iterations with
// fine-grained vmcnt, avoiding the m97-structure barrier drain.
// Fragment layout (i8 16x16x64): A[m = lane&15][k = (lane>>4)*16 + byte].
__global__ __launch_bounds__(256, 4) void gemm_i8_kernel(
    const signed char* __restrict__ A,   // packed x [S,K] int8
    const signed char* __restrict__ B,   // packed w [O,K] int8
    const float* __restrict__ sx, const float* __restrict__ sw,
    const float* __restrict__ sy, float* __restrict__ out) {
  const int tid = threadIdx.x;
  const int wave = tid >> 6;
  const int lane = tid & 63;
  const int wm = wave >> 1;  // 0..1: wave row in block
  const int wn = wave & 1;   // 0..1: wave col in block
  const int rowBase = blockIdx.y * BM;
  const int colBase = blockIdx.x * BN;

  const int fr = lane & 15;          // fragment row (m for A, n for B)
  const int kq = (lane >> 4) * 16;   // K-chunk byte offset for this quad

  const signed char* pA = A + (size_t)(rowBase + wm * 64 + fr) * K_DIM + kq;
  const signed char* pB = B + (size_t)(colBase + wn * 64 + fr) * K_DIM + kq;

  i32x4 acc[4][4] = {};

#pragma unroll 2
  for (int k0 = 0; k0 < K_DIM; k0 += BK) {
    i32x4 af[4], bf[4];
#pragma unroll
    for (int mi = 0; mi < 4; ++mi)
      af[mi] = *(const i32x4*)(pA + (size_t)mi * 16 * K_DIM + k0);
#pragma unroll
    for (int ni = 0; ni < 4; ++ni)
      bf[ni] = *(const i32x4*)(pB + (size_t)ni * 16 * K_DIM + k0);

#pragma unroll
    for (int mi = 0; mi < 4; ++mi)
#pragma unroll
      for (int ni = 0; ni < 4; ++ni)
        acc[mi][ni] =
            __builtin_amdgcn_mfma_i32_16x16x64_i8(af[mi], bf[ni], acc[mi][ni], 0, 0, 0);
  }

  // Epilogue. C/D layout: col = lane&15, row = (lane>>4)*4 + reg.
  const float sxw = sx[0] * sw[0];
  const int quad = lane >> 4;
#pragma unroll
  for (int mi = 0; mi < 4; ++mi) {
#pragma unroll
    for (int r = 0; r < 4; ++r) {
      const int s = rowBase + wm * 64 + mi * 16 + quad * 4 + r;
      const float rs = sxw / sy[s];
      float* orow = out + (size_t)s * O_DIM + colBase + wn * 64 + fr;
#pragma unroll
      for (int ni = 0; ni < 4; ++ni) {
        float f = rintf((float)acc[mi][ni][r] * rs);
        f = fminf(127.0f, fmaxf(-128.0f, f));
        orow[ni * 16] = f;
      }
    }
  }
}

extern "C" void kernel_launch(void* const* d_in, const int* in_sizes, int n_in,
                              void* d_out, int out_size, void* d_ws, size_t ws_size,
                              hipStream_t stream) {
  const int* x = (const int*)d_in[0];        // [S,K] int8 values as int32
  const int* w = (const int*)d_in[1];        // [O,K] int8 values as int32
  const float* sx = (const float*)d_in[2];
  const float* sw = (const float*)d_in[3];
  const float* sy = (const float*)d_in[4];   // [S]
  float* out = (float*)d_out;

  unsigned int* xq = (unsigned int*)d_ws;                         // 8 MB
  unsigned int* wq = xq + (size_t)S_DIM * K_DIM / 4;              // 4 MB

  const int total = S_DIM * K_DIM / 4 + O_DIM * K_DIM / 4;  // 3M threads
  pack_kernel<<<(total + 255) / 256, 256, 0, stream>>>(
      x, w, sy, xq, wq, out + (size_t)S_DIM * O_DIM);

  dim3 grid(O_DIM / BN, S_DIM / BM);  // (32, 64)
  gemm_i8_kernel<<<grid, 256, 0, stream>>>(
      (const signed char*)xq, (const signed char*)wq, sx, sw, sy, out);
}

// Round 3
// 203.810 us; speedup vs baseline: 1.3809x; 1.3809x over previous
//
#include <hip/hip_runtime.h>

// Problem: S=8192, K=1024, O=4096
// out_q[s,o] = clip(round(int8dot(x[s,:], w[o,:]) * sx*sw/sy[s]), -128, 127)
// d_out = [ out_q as float (S*O) | scale_y (S) ]

#define S_DIM 8192
#define K_DIM 1024
#define O_DIM 4096
#define BM 128
#define BN 128
#define BK 64
#define NITER (K_DIM / BK)

using i32x4 = __attribute__((ext_vector_type(4))) int;

__device__ __forceinline__ void load_lds16(const void* g, void* l) {
  __builtin_amdgcn_global_load_lds(
      (const __attribute__((address_space(1))) void*)g,
      (__attribute__((address_space(3))) void*)l, 16, 0, 0);
}

// ---------------- pack: int32 -> int8 for x and w, plus scale_y passthrough ----
__global__ void pack_kernel(const int* __restrict__ xi, const int* __restrict__ wi,
                            const float* __restrict__ sy,
                            unsigned int* __restrict__ xq, unsigned int* __restrict__ wq,
                            float* __restrict__ out_sy) {
  const int idx = blockIdx.x * blockDim.x + threadIdx.x;
  const int nx = S_DIM * K_DIM / 4;  // 2M packed words
  const int nw = O_DIM * K_DIM / 4;  // 1M packed words
  if (idx < nx) {
    int4 v = ((const int4*)xi)[idx];
    unsigned int p = (v.x & 0xff) | ((v.y & 0xff) << 8) |
                     ((v.z & 0xff) << 16) | ((unsigned)(v.w & 0xff) << 24);
    xq[idx] = p;
  } else if (idx < nx + nw) {
    const int j = idx - nx;
    int4 v = ((const int4*)wi)[j];
    unsigned int p = (v.x & 0xff) | ((v.y & 0xff) << 8) |
                     ((v.z & 0xff) << 16) | ((unsigned)(v.w & 0xff) << 24);
    wq[j] = p;
  }
  if (idx < S_DIM) out_sy[idx] = sy[idx];
}

// ---------------- int8 MFMA GEMM, double-buffered LDS pipeline ----------------
// Block: 256 threads = 4 waves in 2x2; each wave owns a 64x64 sub-tile as a
// 4x4 grid of 16x16 MFMA tiles (mfma_i32_16x16x64_i8, one per tile per K-step).
// Double-buffered LDS (2 x 8KB per operand), ONE barrier per K-iter:
//   barrier(drains prev stage's vmcnt) -> issue async stage of tile k+1 into
//   other buffer -> compute tile k. The vmcnt drain overlaps a full compute
//   phase, removing the m97-structure barrier-drain stall.
// Staging: global_load_lds width=16, LDS dest = wave-uniform base + lane*16.
__global__ __launch_bounds__(256, 4) void gemm_i8_kernel(
    const signed char* __restrict__ A,   // packed x [S,K] int8
    const signed char* __restrict__ B,   // packed w [O,K] int8
    const float* __restrict__ sx, const float* __restrict__ sw,
    const float* __restrict__ sy, float* __restrict__ out) {
  __shared__ __align__(16) signed char As[2][BM * BK];
  __shared__ __align__(16) signed char Bs[2][BN * BK];

  const int tid = threadIdx.x;
  const int wave = tid >> 6;
  const int lane = tid & 63;
  const int wm = wave >> 1;  // 0..1: wave row in block
  const int wn = wave & 1;   // 0..1: wave col in block
  const int rowBase = blockIdx.y * BM;
  const int colBase = blockIdx.x * BN;

  // Staging map: round r (r=0,1) covers block rows [r*64, r*64+64):
  // lane -> row = r*64 + wave*16 + lane/4, col = (lane%4)*16.
  // LDS byte = r*4096 + wave*1024 + lane*16 (wave-uniform base + lane*16).
  const int sRow = wave * 16 + (lane >> 2);
  const int sCol = (lane & 3) * 16;
  const signed char* gA = A + (size_t)(rowBase + sRow) * K_DIM + sCol;
  const signed char* gB = B + (size_t)(colBase + sRow) * K_DIM + sCol;

  i32x4 acc[4][4] = {};

  const int fr = lane & 15;          // row within 16x16 fragment
  const int fq = (lane >> 4) * 16;   // K-chunk byte offset for this quad

  // Prologue: stage tile 0 into buffer 0.
  {
    signed char* lA = As[0] + wave * 1024;
    signed char* lB = Bs[0] + wave * 1024;
    load_lds16(gA, lA);
    load_lds16(gA + (size_t)64 * K_DIM, lA + 4096);
    load_lds16(gB, lB);
    load_lds16(gB + (size_t)64 * K_DIM, lB + 4096);
  }

  for (int it = 0; it < NITER; ++it) {
    __syncthreads();  // drains vmcnt of stage issued last iter; buffer ready

    if (it + 1 < NITER) {  // async-stage next tile into the other buffer
      const int nb = (it + 1) & 1;
      const int k0 = (it + 1) * BK;
      signed char* lA = As[nb] + wave * 1024;
      signed char* lB = Bs[nb] + wave * 1024;
      load_lds16(gA + k0, lA);
      load_lds16(gA + (size_t)64 * K_DIM + k0, lA + 4096);
      load_lds16(gB + k0, lB);
      load_lds16(gB + (size_t)64 * K_DIM + k0, lB + 4096);
    }

    const signed char* curA = As[it & 1];
    const signed char* curB = Bs[it & 1];
    i32x4 af[4], bf[4];
#pragma unroll
    for (int mi = 0; mi < 4; ++mi)
      af[mi] = *(const i32x4*)(curA + (wm * 64 + mi * 16 + fr) * BK + fq);
#pragma unroll
    for (int ni = 0; ni < 4; ++ni)
      bf[ni] = *(const i32x4*)(curB + (wn * 64 + ni * 16 + fr) * BK + fq);

#pragma unroll
    for (int mi = 0; mi < 4; ++mi)
#pragma unroll
      for (int ni = 0; ni < 4; ++ni)
        acc[mi][ni] =
            __builtin_amdgcn_mfma_i32_16x16x64_i8(af[mi], bf[ni], acc[mi][ni], 0, 0, 0);
  }

  // Epilogue. C/D layout: col = lane&15, row = (lane>>4)*4 + reg.
  const float sxw = sx[0] * sw[0];
  const int quad = lane >> 4;
#pragma unroll
  for (int mi = 0; mi < 4; ++mi) {
#pragma unroll
    for (int r = 0; r < 4; ++r) {
      const int s = rowBase + wm * 64 + mi * 16 + quad * 4 + r;
      const float rs = sxw / sy[s];
      float* orow = out + (size_t)s * O_DIM + colBase + wn * 64 + fr;
#pragma unroll
      for (int ni = 0; ni < 4; ++ni) {
        float f = rintf((float)acc[mi][ni][r] * rs);
        f = fminf(127.0f, fmaxf(-128.0f, f));
        orow[ni * 16] = f;
      }
    }
  }
}

extern "C" void kernel_launch(void* const* d_in, const int* in_sizes, int n_in,
                              void* d_out, int out_size, void* d_ws, size_t ws_size,
                              hipStream_t stream) {
  const int* x = (const int*)d_in[0];        // [S,K] int8 values as int32
  const int* w = (const int*)d_in[1];        // [O,K] int8 values as int32
  const float* sx = (const float*)d_in[2];
  const float* sw = (const float*)d_in[3];
  const float* sy = (const float*)d_in[4];   // [S]
  float* out = (float*)d_out;

  unsigned int* xq = (unsigned int*)d_ws;                         // 8 MB
  unsigned int* wq = xq + (size_t)S_DIM * K_DIM / 4;              // 4 MB

  const int total = S_DIM * K_DIM / 4 + O_DIM * K_DIM / 4;  // 3M threads
  pack_kernel<<<(total + 255) / 256, 256, 0, stream>>>(
      x, w, sy, xq, wq, out + (size_t)S_DIM * O_DIM);

  dim3 grid(O_DIM / BN, S_DIM / BM);  // (32, 64)
  gemm_i8_kernel<<<grid, 256, 0, stream>>>(
      (const signed char*)xq, (const signed char*)wq, sx, sw, sy, out);
}